// Round 15
// baseline (330.380 us; speedup 1.0000x reference)
//
#include <hip/hip_runtime.h>
#include <hip/hip_bf16.h>
#include <stdint.h>

// dims (fixed by the problem)
#define T_TOK 4096
#define NE    8
#define DM    1024
#define FF    4096
#define CAP   1536

typedef __attribute__((ext_vector_type(8))) __bf16 bf16x8;
typedef __attribute__((ext_vector_type(4))) float  f32x4;
struct ushort8 { ushort4 lo, hi; };

__device__ __forceinline__ void gload_lds16(const void* gptr, void* lptr) {
  __builtin_amdgcn_global_load_lds(
      (__attribute__((address_space(1))) void*)(uintptr_t)gptr,
      (__attribute__((address_space(3))) void*)(uintptr_t)lptr,
      16, 0, 0);
}

// ---------------- small prep kernels ----------------

__global__ void conv_x_kernel(const float4* __restrict__ src, ushort4* __restrict__ dst, int n4) {
  int i = blockIdx.x * blockDim.x + threadIdx.x;
  if (i >= n4) return;
  float4 v = src[i];
  ushort4 o;
  o.x = __builtin_bit_cast(unsigned short, __float2bfloat16(v.x));
  o.y = __builtin_bit_cast(unsigned short, __float2bfloat16(v.y));
  o.z = __builtin_bit_cast(unsigned short, __float2bfloat16(v.z));
  o.w = __builtin_bit_cast(unsigned short, __float2bfloat16(v.w));
  dst[i] = o;
}

// transpose+convert: src f32 [B][R][C] -> dst bf16 [B][C][R]; 16B stores.
__global__ __launch_bounds__(256)
void tconv_kernel(const float* __restrict__ src, __hip_bfloat16* __restrict__ dst,
                  int R, int C) {
  __shared__ float tile[64][65];
  const int b  = blockIdx.z;
  const int r0 = blockIdx.y * 64;
  const int c0 = blockIdx.x * 64;
  const float* s = src + (size_t)b * R * C;
  __hip_bfloat16* d = dst + (size_t)b * R * C;
  const int tid = threadIdx.x;
  const int tx = tid & 63, ty = tid >> 6;
#pragma unroll
  for (int rr = ty; rr < 64; rr += 4)
    tile[rr][tx] = s[(size_t)(r0 + rr) * C + c0 + tx];
  __syncthreads();
  const int lg = tid & 7;         // 8 row-groups of 8
  const int cg = tid >> 3;        // 32 col groups
#pragma unroll
  for (int w = 0; w < 2; ++w) {
    const int cc = w * 32 + cg;
    const int r8 = lg * 8;
    ushort8 o;
#pragma unroll
    for (int q = 0; q < 4; ++q) {
      ((unsigned short*)&o.lo)[q] =
          __builtin_bit_cast(unsigned short, __float2bfloat16(tile[r8 + q][cc]));
      ((unsigned short*)&o.hi)[q] =
          __builtin_bit_cast(unsigned short, __float2bfloat16(tile[r8 + 4 + q][cc]));
    }
    *(ushort8*)&d[(size_t)(c0 + cc) * R + r0 + r8] = o;
  }
}

__global__ void router_kernel(const float* __restrict__ rw, int* __restrict__ counts,
                              int* __restrict__ tok_ids, float* __restrict__ gains) {
  int t = blockIdx.x * blockDim.x + threadIdx.x;
  if (t >= T_TOK) return;
#pragma unroll
  for (int e = 0; e < NE; ++e) {
    float w = rw[t * NE + e];
    if (w > 0.f) {
      int pos = atomicAdd(&counts[e], 1);
      if (pos < CAP) {
        tok_ids[e * CAP + pos] = t;
        gains[e * CAP + pos]   = w;
      }
    }
  }
}

// -------- 128x128 grouped MFMA GEMM, BK=64 (R6/R14: the proven structure) --------
// BM=BN=128, BK=64, 256 threads (4 waves, 2x2 of 64x64), mfma 16x16x32 bf16.
// Single-buffered 32 KB LDS, plain __syncthreads, compiler scheduling,
// nt-fastest, no XCD swizzle. XOR swizzle: source chunk ^= (row&7)
// (pre-swizzled global addr, LDS dest linear), read chunk = (fq+4s)^(fr&7);
// conflict-free (SQ_LDS_BANK_CONFLICT = 0, R6-verified).
// R15: pass2 SK=2 (isolated; R10 confounded SK2 with lb4). bias on sp==0.

template <int PASS, int SK>
__global__ __launch_bounds__(256, 2)
void moe_gemm(const __hip_bfloat16* __restrict__ Asrc,
              const __hip_bfloat16* __restrict__ Bsrc,   // [E][NP][K] (B^T, k contiguous)
              const float* __restrict__ bias,            // [E][NP]
              const int* __restrict__ counts,
              const int* __restrict__ tok_ids,
              const float* __restrict__ gains,
              __hip_bfloat16* __restrict__ Hout,         // PASS1 out [E][CAP][FF]
              float* __restrict__ y)                     // PASS2 out [T][DM]
{
  constexpr int K  = (PASS == 1) ? DM : FF;
  constexpr int NP = (PASS == 1) ? FF : DM;
  constexpr int MT = CAP / 128;  // 12
  constexpr int NT = NP / 128;   // 32 / 8
  constexpr int KP = K / SK;
  constexpr int KT = KP / 64;    // 16 / 32

  const int bid   = blockIdx.x;
  const int per_e = MT * NT * SK;
  const int e     = bid / per_e;
  int r           = bid % per_e;
  const int mt    = r / (NT * SK);
  r               = r % (NT * SK);
  const int nt    = r / SK;      // nt fast (R6 geometry), sp fastest
  const int sp    = r % SK;

  const int Ne = min(counts[e], CAP);
  const int m0 = mt * 128;
  if (m0 >= Ne) return;
  const int n0 = nt * 128;
  const int k0 = sp * KP;

  __shared__ alignas(16) __hip_bfloat16 As[128 * 64];
  __shared__ alignas(16) __hip_bfloat16 Bs[128 * 64];

  const int tid  = threadIdx.x;
  const int lane = tid & 63;
  const int wid  = tid >> 6;
  const int wm   = wid >> 1;
  const int wn   = wid & 1;

  // staging: instr i covers rows [i*32, i*32+32); thread row = i*32 + (tid>>3),
  // chunk = tid&7 (16B granules, 8/row). source chunk pre-swizzled ^ (row&7).
  const int srow8 = (tid >> 3) & 7;                 // row&7 (i*32 preserves it)
  const int cs    = ((tid & 7) ^ srow8) * 8;        // element offset in k

  const __hip_bfloat16 *aP[4], *bP[4];
#pragma unroll
  for (int i = 0; i < 4; ++i) {
    const int row = i * 32 + (tid >> 3);
    if (PASS == 1) {
      const int tok = tok_ids[e * CAP + m0 + row];
      aP[i] = Asrc + (size_t)tok * DM + k0 + cs;
    } else {
      aP[i] = Asrc + ((size_t)e * CAP + m0 + row) * FF + k0 + cs;
    }
    bP[i] = Bsrc + ((size_t)e * NP + n0 + row) * K + k0 + cs;
  }

  const char* AsB = (const char*)As;
  const char* BsB = (const char*)Bs;
  const int fr = lane & 15;
  const int fq = lane >> 4;
  // read-side swizzled chunk byte offsets for the two k-halves (s = 0, 1)
  const int kb0 = ((fq + 0) ^ (fr & 7)) << 4;
  const int kb1 = ((fq + 4) ^ (fr & 7)) << 4;

  f32x4 acc[4][4] = {};

  for (int kt = 0; kt < KT; ++kt) {
#pragma unroll
    for (int i = 0; i < 4; ++i)
      gload_lds16(aP[i] + kt * 64, (char*)As + i * 4096 + tid * 16);
#pragma unroll
    for (int i = 0; i < 4; ++i)
      gload_lds16(bP[i] + kt * 64, (char*)Bs + i * 4096 + tid * 16);
    __syncthreads();

#pragma unroll
    for (int s = 0; s < 2; ++s) {
      const int kb = s ? kb1 : kb0;
      bf16x8 af[4], bfr[4];
#pragma unroll
      for (int i = 0; i < 4; ++i)
        af[i] = *(const bf16x8*)(AsB + (wm * 64 + i * 16 + fr) * 128 + kb);
#pragma unroll
      for (int j = 0; j < 4; ++j)
        bfr[j] = *(const bf16x8*)(BsB + (wn * 64 + j * 16 + fr) * 128 + kb);
#pragma unroll
      for (int i = 0; i < 4; ++i)
#pragma unroll
        for (int j = 0; j < 4; ++j)
          acc[i][j] = __builtin_amdgcn_mfma_f32_16x16x32_bf16(af[i], bfr[j], acc[i][j], 0, 0, 0);
    }
    __syncthreads();
  }

  const int colb = n0 + wn * 64 + fr;
  if (PASS == 1) {
#pragma unroll
    for (int j = 0; j < 4; ++j) {
      const float bv = bias[(size_t)e * NP + colb + j * 16];
#pragma unroll
      for (int i = 0; i < 4; ++i)
#pragma unroll
        for (int rr = 0; rr < 4; ++rr) {
          const int row = m0 + wm * 64 + i * 16 + fq * 4 + rr;
          float v = acc[i][j][rr] + bv;
          v = v > 0.f ? v : 0.f;
          Hout[((size_t)e * CAP + row) * FF + colb + j * 16] = __float2bfloat16(v);
        }
    }
  } else {
    float bv[4];
#pragma unroll
    for (int j = 0; j < 4; ++j)
      bv[j] = (sp == 0) ? bias[(size_t)e * NP + colb + j * 16] : 0.f;
#pragma unroll
    for (int i = 0; i < 4; ++i)
#pragma unroll
      for (int rr = 0; rr < 4; ++rr) {
        const int row  = m0 + wm * 64 + i * 16 + fq * 4 + rr;
        const int slot = e * CAP + row;
        const float g  = gains[slot];
        if (g != 0.f) {
          const int tok = tok_ids[slot];
          float* yrow = y + (size_t)tok * DM + colb;
#pragma unroll
          for (int j = 0; j < 4; ++j)
            atomicAdd(yrow + j * 16, (acc[i][j][rr] + bv[j]) * g);
        }
      }
  }
}

// ---------------- launch ----------------

extern "C" void kernel_launch(void* const* d_in, const int* in_sizes, int n_in,
                              void* d_out, int out_size, void* d_ws, size_t ws_size,
                              hipStream_t stream) {
  const float* x  = (const float*)d_in[0];
  // d_in[1] = route_mask (bool) — unused: mask == (route_weight > 0)
  const float* rw = (const float*)d_in[2];
  const float* W1 = (const float*)d_in[3];
  const float* b1 = (const float*)d_in[4];
  const float* W2 = (const float*)d_in[5];
  const float* b2 = (const float*)d_in[6];
  float* y = (float*)d_out;

  char* ws = (char*)d_ws;
  size_t off = 0;
  auto alloc = [&](size_t bytes) {
    void* p = ws + off;
    off = (off + bytes + 255) & ~(size_t)255;
    return p;
  };
  __hip_bfloat16* xb  = (__hip_bfloat16*)alloc((size_t)T_TOK * DM * 2);       // 8.4 MB
  __hip_bfloat16* w1t = (__hip_bfloat16*)alloc((size_t)NE * DM * FF * 2);     // 67 MB  [E][F][D]
  __hip_bfloat16* w2t = (__hip_bfloat16*)alloc((size_t)NE * FF * DM * 2);     // 67 MB  [E][D][F]
  __hip_bfloat16* Hb  = (__hip_bfloat16*)alloc((size_t)NE * CAP * FF * 2);    // 100 MB [E][CAP][F]
  int*   counts  = (int*)alloc(NE * sizeof(int));
  int*   tok_ids = (int*)alloc((size_t)NE * CAP * sizeof(int));
  float* gains   = (float*)alloc((size_t)NE * CAP * sizeof(float));
  (void)ws_size; (void)in_sizes; (void)n_in; (void)out_size;

  hipMemsetAsync(y, 0, (size_t)T_TOK * DM * sizeof(float), stream);
  // one memset over counts+tok_ids+gains: unwritten slots stay 0 (pad semantics)
  const size_t ctl_bytes = (size_t)((char*)(gains + NE * CAP) - (char*)counts);
  hipMemsetAsync(counts, 0, ctl_bytes, stream);

  conv_x_kernel<<<(T_TOK * DM / 4 + 255) / 256, 256, 0, stream>>>(
      (const float4*)x, (ushort4*)xb, T_TOK * DM / 4);
  tconv_kernel<<<dim3(FF / 64, DM / 64, NE), 256, 0, stream>>>(W1, w1t, DM, FF);
  tconv_kernel<<<dim3(DM / 64, FF / 64, NE), 256, 0, stream>>>(W2, w2t, FF, DM);
  router_kernel<<<(T_TOK + 255) / 256, 256, 0, stream>>>(rw, counts, tok_ids, gains);

  moe_gemm<1, 1><<<NE * (CAP / 128) * (FF / 128), 256, 0, stream>>>(
      xb, w1t, b1, counts, tok_ids, gains, Hb, nullptr);
  moe_gemm<2, 2><<<NE * (CAP / 128) * (DM / 128) * 2, 256, 0, stream>>>(
      Hb, w2t, b2, counts, tok_ids, gains, nullptr, y);
}

// Round 16
// 320.901 us; speedup vs baseline: 1.0295x; 1.0295x over previous
//
#include <hip/hip_runtime.h>
#include <hip/hip_bf16.h>
#include <stdint.h>

// dims (fixed by the problem)
#define T_TOK 4096
#define NE    8
#define DM    1024
#define FF    4096
#define CAP   1536

typedef __attribute__((ext_vector_type(8))) __bf16 bf16x8;
typedef __attribute__((ext_vector_type(4))) float  f32x4;
struct ushort8 { ushort4 lo, hi; };

__device__ __forceinline__ void gload_lds16(const void* gptr, void* lptr) {
  __builtin_amdgcn_global_load_lds(
      (__attribute__((address_space(1))) void*)(uintptr_t)gptr,
      (__attribute__((address_space(3))) void*)(uintptr_t)lptr,
      16, 0, 0);
}

// ---------------- small prep kernels ----------------

__global__ void conv_x_kernel(const float4* __restrict__ src, ushort4* __restrict__ dst, int n4) {
  int i = blockIdx.x * blockDim.x + threadIdx.x;
  if (i >= n4) return;
  float4 v = src[i];
  ushort4 o;
  o.x = __builtin_bit_cast(unsigned short, __float2bfloat16(v.x));
  o.y = __builtin_bit_cast(unsigned short, __float2bfloat16(v.y));
  o.z = __builtin_bit_cast(unsigned short, __float2bfloat16(v.z));
  o.w = __builtin_bit_cast(unsigned short, __float2bfloat16(v.w));
  dst[i] = o;
}

// transpose+convert: src f32 [B][R][C] -> dst bf16 [B][C][R]; 16B stores.
__global__ __launch_bounds__(256)
void tconv_kernel(const float* __restrict__ src, __hip_bfloat16* __restrict__ dst,
                  int R, int C) {
  __shared__ float tile[64][65];
  const int b  = blockIdx.z;
  const int r0 = blockIdx.y * 64;
  const int c0 = blockIdx.x * 64;
  const float* s = src + (size_t)b * R * C;
  __hip_bfloat16* d = dst + (size_t)b * R * C;
  const int tid = threadIdx.x;
  const int tx = tid & 63, ty = tid >> 6;
#pragma unroll
  for (int rr = ty; rr < 64; rr += 4)
    tile[rr][tx] = s[(size_t)(r0 + rr) * C + c0 + tx];
  __syncthreads();
  const int lg = tid & 7;         // 8 row-groups of 8
  const int cg = tid >> 3;        // 32 col groups
#pragma unroll
  for (int w = 0; w < 2; ++w) {
    const int cc = w * 32 + cg;
    const int r8 = lg * 8;
    ushort8 o;
#pragma unroll
    for (int q = 0; q < 4; ++q) {
      ((unsigned short*)&o.lo)[q] =
          __builtin_bit_cast(unsigned short, __float2bfloat16(tile[r8 + q][cc]));
      ((unsigned short*)&o.hi)[q] =
          __builtin_bit_cast(unsigned short, __float2bfloat16(tile[r8 + 4 + q][cc]));
    }
    *(ushort8*)&d[(size_t)(c0 + cc) * R + r0 + r8] = o;
  }
}

__global__ void router_kernel(const float* __restrict__ rw, int* __restrict__ counts,
                              int* __restrict__ tok_ids, float* __restrict__ gains) {
  int t = blockIdx.x * blockDim.x + threadIdx.x;
  if (t >= T_TOK) return;
#pragma unroll
  for (int e = 0; e < NE; ++e) {
    float w = rw[t * NE + e];
    if (w > 0.f) {
      int pos = atomicAdd(&counts[e], 1);
      if (pos < CAP) {
        tok_ids[e * CAP + pos] = t;
        gains[e * CAP + pos]   = w;
      }
    }
  }
}

// -------- 128x128 grouped MFMA GEMM, BK=64 (R6/R14: the proven structure) --------
// BM=BN=128, BK=64, 256 threads (4 waves, 2x2 of 64x64), mfma 16x16x32 bf16.
// Single-buffered 32 KB LDS, plain __syncthreads, compiler scheduling,
// nt-fastest, no XCD swizzle. XOR swizzle: source chunk ^= (row&7)
// (pre-swizzled global addr, LDS dest linear), read chunk = (fq+4s)^(fr&7);
// conflict-free (SQ_LDS_BANK_CONFLICT = 0, R6-verified).
// Session ledger: BK 32->64 amortization was the only GEMM-level win; all
// pipelining/8-phase/BK=128/256-tile/LDS-free/occupancy/split-K variants
// regressed (R2-R15). This is the converged structure.

template <int PASS>
__global__ __launch_bounds__(256, 2)
void moe_gemm(const __hip_bfloat16* __restrict__ Asrc,
              const __hip_bfloat16* __restrict__ Bsrc,   // [E][NP][K] (B^T, k contiguous)
              const float* __restrict__ bias,            // [E][NP]
              const int* __restrict__ counts,
              const int* __restrict__ tok_ids,
              const float* __restrict__ gains,
              __hip_bfloat16* __restrict__ Hout,         // PASS1 out [E][CAP][FF]
              float* __restrict__ y)                     // PASS2 out [T][DM]
{
  constexpr int K  = (PASS == 1) ? DM : FF;
  constexpr int NP = (PASS == 1) ? FF : DM;
  constexpr int MT = CAP / 128;  // 12
  constexpr int NT = NP / 128;   // 32 / 8
  constexpr int KT = K / 64;     // 16 / 64

  const int bid = blockIdx.x;
  const int e   = bid / (MT * NT);
  const int rem = bid % (MT * NT);
  const int mt  = rem / NT;
  const int nt  = rem % NT;      // nt fastest (R6 geometry)

  const int Ne = min(counts[e], CAP);
  const int m0 = mt * 128;
  if (m0 >= Ne) return;
  const int n0 = nt * 128;

  __shared__ alignas(16) __hip_bfloat16 As[128 * 64];
  __shared__ alignas(16) __hip_bfloat16 Bs[128 * 64];

  const int tid  = threadIdx.x;
  const int lane = tid & 63;
  const int wid  = tid >> 6;
  const int wm   = wid >> 1;
  const int wn   = wid & 1;

  // staging: instr i covers rows [i*32, i*32+32); thread row = i*32 + (tid>>3),
  // chunk = tid&7 (16B granules, 8/row). source chunk pre-swizzled ^ (row&7).
  const int srow8 = (tid >> 3) & 7;                 // row&7 (i*32 preserves it)
  const int cs    = ((tid & 7) ^ srow8) * 8;        // element offset in k

  const __hip_bfloat16 *aP[4], *bP[4];
#pragma unroll
  for (int i = 0; i < 4; ++i) {
    const int row = i * 32 + (tid >> 3);
    if (PASS == 1) {
      const int tok = tok_ids[e * CAP + m0 + row];
      aP[i] = Asrc + (size_t)tok * DM + cs;
    } else {
      aP[i] = Asrc + ((size_t)e * CAP + m0 + row) * FF + cs;
    }
    bP[i] = Bsrc + ((size_t)e * NP + n0 + row) * K + cs;
  }

  const char* AsB = (const char*)As;
  const char* BsB = (const char*)Bs;
  const int fr = lane & 15;
  const int fq = lane >> 4;
  // read-side swizzled chunk byte offsets for the two k-halves (s = 0, 1)
  const int kb0 = ((fq + 0) ^ (fr & 7)) << 4;
  const int kb1 = ((fq + 4) ^ (fr & 7)) << 4;

  f32x4 acc[4][4] = {};

  for (int kt = 0; kt < KT; ++kt) {
#pragma unroll
    for (int i = 0; i < 4; ++i)
      gload_lds16(aP[i] + kt * 64, (char*)As + i * 4096 + tid * 16);
#pragma unroll
    for (int i = 0; i < 4; ++i)
      gload_lds16(bP[i] + kt * 64, (char*)Bs + i * 4096 + tid * 16);
    __syncthreads();

#pragma unroll
    for (int s = 0; s < 2; ++s) {
      const int kb = s ? kb1 : kb0;
      bf16x8 af[4], bfr[4];
#pragma unroll
      for (int i = 0; i < 4; ++i)
        af[i] = *(const bf16x8*)(AsB + (wm * 64 + i * 16 + fr) * 128 + kb);
#pragma unroll
      for (int j = 0; j < 4; ++j)
        bfr[j] = *(const bf16x8*)(BsB + (wn * 64 + j * 16 + fr) * 128 + kb);
#pragma unroll
      for (int i = 0; i < 4; ++i)
#pragma unroll
        for (int j = 0; j < 4; ++j)
          acc[i][j] = __builtin_amdgcn_mfma_f32_16x16x32_bf16(af[i], bfr[j], acc[i][j], 0, 0, 0);
    }
    __syncthreads();
  }

  const int colb = n0 + wn * 64 + fr;
  if (PASS == 1) {
#pragma unroll
    for (int j = 0; j < 4; ++j) {
      const float bv = bias[(size_t)e * NP + colb + j * 16];
#pragma unroll
      for (int i = 0; i < 4; ++i)
#pragma unroll
        for (int rr = 0; rr < 4; ++rr) {
          const int row = m0 + wm * 64 + i * 16 + fq * 4 + rr;
          float v = acc[i][j][rr] + bv;
          v = v > 0.f ? v : 0.f;
          Hout[((size_t)e * CAP + row) * FF + colb + j * 16] = __float2bfloat16(v);
        }
    }
  } else {
    float bv[4];
#pragma unroll
    for (int j = 0; j < 4; ++j) bv[j] = bias[(size_t)e * NP + colb + j * 16];
#pragma unroll
    for (int i = 0; i < 4; ++i)
#pragma unroll
      for (int rr = 0; rr < 4; ++rr) {
        const int row  = m0 + wm * 64 + i * 16 + fq * 4 + rr;
        const int slot = e * CAP + row;
        const float g  = gains[slot];
        if (g != 0.f) {
          const int tok = tok_ids[slot];
          float* yrow = y + (size_t)tok * DM + colb;
#pragma unroll
          for (int j = 0; j < 4; ++j)
            atomicAdd(yrow + j * 16, (acc[i][j][rr] + bv[j]) * g);
        }
      }
  }
}

// ---------------- launch ----------------

extern "C" void kernel_launch(void* const* d_in, const int* in_sizes, int n_in,
                              void* d_out, int out_size, void* d_ws, size_t ws_size,
                              hipStream_t stream) {
  const float* x  = (const float*)d_in[0];
  // d_in[1] = route_mask (bool) — unused: mask == (route_weight > 0)
  const float* rw = (const float*)d_in[2];
  const float* W1 = (const float*)d_in[3];
  const float* b1 = (const float*)d_in[4];
  const float* W2 = (const float*)d_in[5];
  const float* b2 = (const float*)d_in[6];
  float* y = (float*)d_out;

  char* ws = (char*)d_ws;
  size_t off = 0;
  auto alloc = [&](size_t bytes) {
    void* p = ws + off;
    off = (off + bytes + 255) & ~(size_t)255;
    return p;
  };
  __hip_bfloat16* xb  = (__hip_bfloat16*)alloc((size_t)T_TOK * DM * 2);       // 8.4 MB
  __hip_bfloat16* w1t = (__hip_bfloat16*)alloc((size_t)NE * DM * FF * 2);     // 67 MB  [E][F][D]
  __hip_bfloat16* w2t = (__hip_bfloat16*)alloc((size_t)NE * FF * DM * 2);     // 67 MB  [E][D][F]
  __hip_bfloat16* Hb  = (__hip_bfloat16*)alloc((size_t)NE * CAP * FF * 2);    // 100 MB [E][CAP][F]
  int*   counts  = (int*)alloc(NE * sizeof(int));
  int*   tok_ids = (int*)alloc((size_t)NE * CAP * sizeof(int));
  float* gains   = (float*)alloc((size_t)NE * CAP * sizeof(float));
  (void)ws_size; (void)in_sizes; (void)n_in; (void)out_size;

  hipMemsetAsync(y, 0, (size_t)T_TOK * DM * sizeof(float), stream);
  // one memset over counts+tok_ids+gains: unwritten slots stay 0 (pad semantics)
  const size_t ctl_bytes = (size_t)((char*)(gains + NE * CAP) - (char*)counts);
  hipMemsetAsync(counts, 0, ctl_bytes, stream);

  conv_x_kernel<<<(T_TOK * DM / 4 + 255) / 256, 256, 0, stream>>>(
      (const float4*)x, (ushort4*)xb, T_TOK * DM / 4);
  tconv_kernel<<<dim3(FF / 64, DM / 64, NE), 256, 0, stream>>>(W1, w1t, DM, FF);
  tconv_kernel<<<dim3(DM / 64, FF / 64, NE), 256, 0, stream>>>(W2, w2t, FF, DM);
  router_kernel<<<(T_TOK + 255) / 256, 256, 0, stream>>>(rw, counts, tok_ids, gains);

  moe_gemm<1><<<NE * (CAP / 128) * (FF / 128), 256, 0, stream>>>(
      xb, w1t, b1, counts, tok_ids, gains, Hb, nullptr);
  moe_gemm<2><<<NE * (CAP / 128) * (DM / 128), 256, 0, stream>>>(
      Hb, w2t, b2, counts, tok_ids, gains, nullptr, y);
}